// Round 5
// baseline (7201.966 us; speedup 1.0000x reference)
//
#include <hip/hip_runtime.h>
#include <hip/hip_bf16.h>

typedef __attribute__((ext_vector_type(8))) short short8;
typedef __attribute__((ext_vector_type(4))) float floatx4;
typedef __attribute__((ext_vector_type(4))) unsigned int uintx4;
typedef unsigned int u32;

#define Bb 32
#define Ss 2048
#define Ii 256
#define Hh 256

// ws layout:
//   [4096, 53248)   data: u32 data[3][32][128] — value-validated h exchange, slot = t%3
//                   word = packed bf16 pair | 0x4000 (written, lo bit14) | parity<<30 (hi bit14)
//                   (|h|<=1.0 => bf16 bit14 always 0 => both bits free; 0xAAAAAAAA and
//                    0x00000000 poison both fail the check)
//   [65536, ...)    gx: bf16 pre-activation fragments (proven layout)
#define DATA_OFF 4096
#define GX_OFF   65536
// container-safety: one global timeout budget (~0.16s), then permanent dead-latch
#define RETRY_DEAD (1u << 17)

__device__ __forceinline__ unsigned short f2bf(float f) {
    unsigned int u = __float_as_uint(f);
    u += 0x7fffu + ((u >> 16) & 1u);   // RNE
    return (unsigned short)(u >> 16);
}
__device__ __forceinline__ float bf2f_lo(u32 w) { return __uint_as_float(w << 16); }
__device__ __forceinline__ float bf2f_hi(u32 w) { return __uint_as_float(w & 0xffff0000u); }

__device__ __forceinline__ float fast_sigmoid(float x) {
    return __builtin_amdgcn_rcpf(1.0f + __expf(-x));
}
__device__ __forceinline__ float fast_tanh(float x) {
    return 1.0f - 2.0f * __builtin_amdgcn_rcpf(__expf(2.0f * x) + 1.0f);
}

// device-coherent batched poll load (sc0 sc1 = system scope, served at MALL — proven path)
__device__ __forceinline__ void data_load8_s(const u32* pd, uintx4 v[8]) {
    asm volatile("global_load_dwordx4 %0, %8, off sc0 sc1\n\t"
                 "global_load_dwordx4 %1, %8, off offset:64 sc0 sc1\n\t"
                 "global_load_dwordx4 %2, %8, off offset:128 sc0 sc1\n\t"
                 "global_load_dwordx4 %3, %8, off offset:192 sc0 sc1\n\t"
                 "global_load_dwordx4 %4, %8, off offset:256 sc0 sc1\n\t"
                 "global_load_dwordx4 %5, %8, off offset:320 sc0 sc1\n\t"
                 "global_load_dwordx4 %6, %8, off offset:384 sc0 sc1\n\t"
                 "global_load_dwordx4 %7, %8, off offset:448 sc0 sc1\n\t"
                 "s_waitcnt vmcnt(0)"
                 : "=v"(v[0]), "=v"(v[1]), "=v"(v[2]), "=v"(v[3]),
                   "=v"(v[4]), "=v"(v[5]), "=v"(v[6]), "=v"(v[7])
                 : "v"(pd) : "memory");
}

// ---------------- Phase 1: gx[t] = x_t @ Wx_all + b_all (byte-identical, proven)
__global__ __launch_bounds__(256, 2)
void lstm_gx_kernel(const float* __restrict__ x,
                    const float* __restrict__ Wf, const float* __restrict__ bfp,
                    const float* __restrict__ Wi, const float* __restrict__ bip,
                    const float* __restrict__ Wc, const float* __restrict__ bcp,
                    const float* __restrict__ Wo, const float* __restrict__ bop,
                    u32* __restrict__ gx)
{
    const int tid = threadIdx.x, wave = tid >> 6, lane = tid & 63;
    const int ln = lane & 15, lg = lane >> 4;
    const int combo = blockIdx.x & 7;
    const int tbase = (blockIdx.x >> 3) * 8;
    const int wg = ((combo & 1) << 2) + wave;
    const int chalf = (combo >> 1) & 1, mtile = combo >> 2;
    const int j0 = wg * 32 + chalf * 16, r0 = mtile * 16;
    const int wv = wg * 4 + chalf * 2 + mtile;

    const float* Wg[4] = {Wf, Wi, Wc, Wo};
    const float* bg[4] = {bfp, bip, bcp, bop};
    float bias[4];
#pragma unroll
    for (int g = 0; g < 4; ++g) bias[g] = bg[g][j0 + ln];

    short8 Bf[4][8];
#pragma unroll
    for (int g = 0; g < 4; ++g)
#pragma unroll
        for (int ks = 0; ks < 8; ++ks) {
            short8 v;
#pragma unroll
            for (int i = 0; i < 8; ++i) {
                int k = 256 + 32 * ks + 8 * lg + i;
                v[i] = (short)f2bf(Wg[g][k * Hh + (j0 + ln)]);
            }
            Bf[g][ks] = v;
        }

    for (int it = 0; it < 8; ++it) {
        int t = tbase + it;
        short8 xf[8];
#pragma unroll
        for (int ks = 0; ks < 8; ++ks) {
            const float* px = x + (r0 + ln) * (Ss * Ii) + t * Ii + 32 * ks + 8 * lg;
            floatx4 a = *(const floatx4*)px;
            floatx4 b = *(const floatx4*)(px + 4);
            short8 v;
#pragma unroll
            for (int q = 0; q < 4; ++q) { v[q] = (short)f2bf(a[q]); v[4 + q] = (short)f2bf(b[q]); }
            xf[ks] = v;
        }
        floatx4 acc[4];
#pragma unroll
        for (int g = 0; g < 4; ++g) acc[g] = (floatx4){0.f, 0.f, 0.f, 0.f};
#pragma unroll
        for (int ks = 0; ks < 8; ++ks)
#pragma unroll
            for (int g = 0; g < 4; ++g)
                acc[g] = __builtin_amdgcn_mfma_f32_16x16x32_bf16(xf[ks], Bf[g][ks], acc[g], 0, 0, 0);

        u32 o[8];
#pragma unroll
        for (int g = 0; g < 4; ++g)
#pragma unroll
            for (int rp = 0; rp < 2; ++rp) {
                float v0 = acc[g][2 * rp] + bias[g];
                float v1 = acc[g][2 * rp + 1] + bias[g];
                o[g * 2 + rp] = (u32)f2bf(v0) | ((u32)f2bf(v1) << 16);
            }
        u32* dst = gx + ((size_t)(t * 32 + wv) * 64 + lane) * 8;
        ((uintx4*)dst)[0] = (uintx4){o[0], o[1], o[2], o[3]};
        ((uintx4*)dst)[1] = (uintx4){o[4], o[5], o[6], o[7]};
    }
}

// issue a 4-step gx window: 8 dwordx4 nt loads (no waitcnt — consumed only after a
// later poll's vmcnt(0)). nt: gx lines are read exactly once; keep them out of MALL
// so the exchange region stays MALL-resident.
#define ISSUE_WIN(A0,A1,B0,B1,C0,C1,D0,D1, Q0,Q1,Q2,Q3)                          \
    asm volatile("global_load_dwordx4 %0, %8, off nt\n\t"                         \
                 "global_load_dwordx4 %1, %8, off offset:16 nt\n\t"               \
                 "global_load_dwordx4 %2, %9, off nt\n\t"                         \
                 "global_load_dwordx4 %3, %9, off offset:16 nt\n\t"               \
                 "global_load_dwordx4 %4, %10, off nt\n\t"                        \
                 "global_load_dwordx4 %5, %10, off offset:16 nt\n\t"              \
                 "global_load_dwordx4 %6, %11, off nt\n\t"                        \
                 "global_load_dwordx4 %7, %11, off offset:16 nt"                  \
                 : "=&v"(A0), "=&v"(A1), "=&v"(B0), "=&v"(B1),                    \
                   "=&v"(C0), "=&v"(C1), "=&v"(D0), "=&v"(D1)                     \
                 : "v"(Q0), "v"(Q1), "v"(Q2), "v"(Q3) : "memory")

// poll slot sr for parity-validated h_{T-1}; result in dv[8].
// sched_barrier(0) (rule #18): nothing that reads async-loaded regs may hoist
// above the vmcnt(0) inside the poll.
#define POLL_STEP(T_) do {                                                        \
    const u32 want_ = 0x4000u | ((u32)(((T_) - 1) & 1) << 30);                    \
    const u32* pd_ = data + sr * 4096 + (16 * mt + ln) * 128 + 4 * lg;            \
    u32 it_ = 0;                                                                  \
    for (;;) {                                                                    \
        data_load8_s(pd_, dv);                                                    \
        if (dead) break;                                                          \
        u32 bad_ = 0;                                                             \
        _Pragma("unroll")                                                         \
        for (int ks = 0; ks < 8; ++ks) {                                          \
            bad_ |= (dv[ks].x & 0x40004000u) ^ want_;                             \
            bad_ |= (dv[ks].y & 0x40004000u) ^ want_;                             \
            bad_ |= (dv[ks].z & 0x40004000u) ^ want_;                             \
            bad_ |= (dv[ks].w & 0x40004000u) ^ want_;                             \
        }                                                                         \
        if (!__any((int)(bad_ != 0))) break;                                      \
        if (++it_ >= RETRY_DEAD) { dead = 1u; break; }                            \
    }                                                                             \
    __builtin_amdgcn_sched_barrier(0);                                            \
} while (0)

#define STEP_BODY(T_, GA_, GB_) do {                                              \
    short8 afr_[8];                                                               \
    _Pragma("unroll")                                                             \
    for (int ks = 0; ks < 8; ++ks) {                                              \
        union { uintx4 u; short8 s; } cv_;                                        \
        cv_.u = (uintx4){dv[ks].x & 0xBFFFBFFFu, dv[ks].y & 0xBFFFBFFFu,          \
                         dv[ks].z & 0xBFFFBFFFu, dv[ks].w & 0xBFFFBFFFu};         \
        afr_[ks] = cv_.s;                                                         \
    }                                                                             \
    floatx4 acc_[4];                                                              \
    acc_[0] = (floatx4){bf2f_lo(GA_.x), bf2f_hi(GA_.x), bf2f_lo(GA_.y), bf2f_hi(GA_.y)}; \
    acc_[1] = (floatx4){bf2f_lo(GA_.z), bf2f_hi(GA_.z), bf2f_lo(GA_.w), bf2f_hi(GA_.w)}; \
    acc_[2] = (floatx4){bf2f_lo(GB_.x), bf2f_hi(GB_.x), bf2f_lo(GB_.y), bf2f_hi(GB_.y)}; \
    acc_[3] = (floatx4){bf2f_lo(GB_.z), bf2f_hi(GB_.z), bf2f_lo(GB_.w), bf2f_hi(GB_.w)}; \
    run_mfma(afr_, acc_);                                                         \
    step_tail(acc_, (T_), sw);                                                    \
    sr = sw; sw = (sw == 2) ? 0 : sw + 1;                                         \
} while (0)

// ---------------- Phase 2: 8 blocks, tag-free value-validated exchange (round-3 proven),
// + windowed nt gx prefetch so gx HBM latency never gates the poll's in-order vmcnt.
__global__ __launch_bounds__(256, 1)
void lstm_rec10(const float* __restrict__ h0,
                const float* __restrict__ c0,
                const float* __restrict__ Wf,
                const float* __restrict__ Wi,
                const float* __restrict__ Wc,
                const float* __restrict__ Wo,
                float* __restrict__ out,
                u32* data, const u32* __restrict__ gx)
{
    const int wg = blockIdx.x;
    const int tid = threadIdx.x;
    const int wave = tid >> 6, lane = tid & 63;
    const int mt = wave & 1, chalf = wave >> 1;   // batch-half, col-block
    const int ln = lane & 15, lg = lane >> 4;
    const int j0 = wg * 32 + chalf * 16;
    const int j = j0 + ln;
    const int wv = wg * 4 + chalf * 2 + mt;       // gx fragment slot (matches writer)

    const float* Wg[4] = {Wf, Wi, Wc, Wo};
    short8 Bfrag[4][8];                            // h-part weights, full K=256
#pragma unroll
    for (int g = 0; g < 4; ++g)
#pragma unroll
        for (int ks = 0; ks < 8; ++ks) {
            short8 v;
#pragma unroll
            for (int i = 0; i < 8; ++i) {
                int k = 32 * ks + 8 * lg + i;
                v[i] = (short)f2bf(Wg[g][k * Hh + j]);
            }
            Bfrag[g][ks] = v;
        }

    float cst[4], hl[4];
#pragma unroll
    for (int r = 0; r < 4; ++r) {
        cst[r] = c0[(16 * mt + 4 * lg + r) * Hh + j];
        hl[r] = 0.0f;
    }

    // gates + state update + encoded fire-and-forget publish + out stores
    auto step_tail = [&](floatx4 (&acc)[4], int t, int sw_) {
        float hnew[4];
#pragma unroll
        for (int r = 0; r < 4; ++r) {
            float fg = fast_sigmoid(acc[0][r]);
            float ig = fast_sigmoid(acc[1][r]);
            float cd = fast_tanh(acc[2][r]);
            float og = fast_sigmoid(acc[3][r]);
            float c  = cst[r] * fg + ig * cd;
            cst[r] = c;
            hnew[r] = og * fast_tanh(c);
            hl[r] = hnew[r];
        }
        const u32 tb = 0x4000u | ((u32)(t & 1) << 30);   // written-bit + parity
        u32 wrd[4];
#pragma unroll
        for (int r = 0; r < 4; ++r) {
            float partner = __shfl_xor(hnew[r], 1);
            wrd[r] = ((u32)f2bf(hnew[r]) | ((u32)f2bf(partner) << 16)) | tb;  // valid on even lanes
        }
        u32* pw = data + sw_ * 4096 + (16 * mt + 4 * lg) * 128 + (j >> 1);
        if ((ln & 1) == 0) {
            asm volatile("global_store_dword %4, %0, off sc0 sc1\n\t"
                         "global_store_dword %4, %1, off offset:512 sc0 sc1\n\t"
                         "global_store_dword %4, %2, off offset:1024 sc0 sc1\n\t"
                         "global_store_dword %4, %3, off offset:1536 sc0 sc1"
                         :: "v"(wrd[0]), "v"(wrd[1]), "v"(wrd[2]), "v"(wrd[3]), "v"(pw)
                         : "memory");
        }
        // NO drain: consumers validate by value; next poll's vmcnt(0) orders slot reuse
#pragma unroll
        for (int r = 0; r < 4; ++r)
            out[(16 * mt + 4 * lg + r) * (Ss * Hh) + t * Hh + j] = hnew[r];
    };

    auto run_mfma = [&](short8 (&afr)[8], floatx4 (&acc)[4]) {
#pragma unroll
        for (int ks = 0; ks < 8; ++ks)
#pragma unroll
            for (int g = 0; g < 4; ++g)
                acc[g] = __builtin_amdgcn_mfma_f32_16x16x32_bf16(afr[ks], Bfrag[g][ks], acc[g], 0, 0, 0);
    };

    uintx4 dv[8];
    u32 dead = 0;

    // gx windows: W = gx[tb..tb+3], N = gx[tb+4..tb+7] (ping-pong, 8 steps/iter)
    uintx4 wA0, wA1, wB0, wB1, wC0, wC1, wD0, wD1;
    uintx4 nA0, nA1, nB0, nB1, nC0, nC1, nD0, nD1;

    // prologue: W <- gx[1..4] (plain loads; latency hides under step 0)
    {
        const uintx4* p;
        p = (const uintx4*)(gx + ((size_t)(1 * 32 + wv) * 64 + lane) * 8); wA0 = p[0]; wA1 = p[1];
        p = (const uintx4*)(gx + ((size_t)(2 * 32 + wv) * 64 + lane) * 8); wB0 = p[0]; wB1 = p[1];
        p = (const uintx4*)(gx + ((size_t)(3 * 32 + wv) * 64 + lane) * 8); wC0 = p[0]; wC1 = p[1];
        p = (const uintx4*)(gx + ((size_t)(4 * 32 + wv) * 64 + lane) * 8); wD0 = p[0]; wD1 = p[1];
    }

    // ---- step 0: A-fragments straight from h0 (global, fully available — no exchange)
    {
        short8 a0[8];
        const float* hr = h0 + (16 * mt + ln) * Hh;
#pragma unroll
        for (int ks = 0; ks < 8; ++ks) {
            floatx4 a = *(const floatx4*)(hr + 32 * ks + 8 * lg);
            floatx4 b = *(const floatx4*)(hr + 32 * ks + 8 * lg + 4);
            short8 v;
#pragma unroll
            for (int q = 0; q < 4; ++q) { v[q] = (short)f2bf(a[q]); v[4 + q] = (short)f2bf(b[q]); }
            a0[ks] = v;
        }
        const uintx4* p = (const uintx4*)(gx + ((size_t)wv * 64 + lane) * 8);
        uintx4 g0 = p[0], g1 = p[1];
        floatx4 acc[4];
        acc[0] = (floatx4){bf2f_lo(g0.x), bf2f_hi(g0.x), bf2f_lo(g0.y), bf2f_hi(g0.y)};
        acc[1] = (floatx4){bf2f_lo(g0.z), bf2f_hi(g0.z), bf2f_lo(g0.w), bf2f_hi(g0.w)};
        acc[2] = (floatx4){bf2f_lo(g1.x), bf2f_hi(g1.x), bf2f_lo(g1.y), bf2f_hi(g1.y)};
        acc[3] = (floatx4){bf2f_lo(g1.z), bf2f_hi(g1.z), bf2f_lo(g1.w), bf2f_hi(g1.w)};
        run_mfma(a0, acc);
        step_tail(acc, 0, 0);
    }

    int sr = 0, sw = 1;

    // ---- main loop: 255 iterations × 8 steps cover t = 1..2040
    for (int tb = 1; tb <= 2033; tb += 8) {
        POLL_STEP(tb);
        {   // issue N <- gx[tb+4..tb+7] right after detect: max overlap before next poll
            const u32* q0 = gx + ((size_t)((tb + 4) * 32 + wv) * 64 + lane) * 8;
            ISSUE_WIN(nA0, nA1, nB0, nB1, nC0, nC1, nD0, nD1,
                      q0, q0 + 16384, q0 + 32768, q0 + 49152);
        }
        STEP_BODY(tb, wA0, wA1);
        POLL_STEP(tb + 1); STEP_BODY(tb + 1, wB0, wB1);
        POLL_STEP(tb + 2); STEP_BODY(tb + 2, wC0, wC1);
        POLL_STEP(tb + 3); STEP_BODY(tb + 3, wD0, wD1);
        POLL_STEP(tb + 4);
        {   // issue W <- gx[tb+8..tb+11] (last iter: 2041..2044, consumed by the tail)
            const u32* q0 = gx + ((size_t)((tb + 8) * 32 + wv) * 64 + lane) * 8;
            ISSUE_WIN(wA0, wA1, wB0, wB1, wC0, wC1, wD0, wD1,
                      q0, q0 + 16384, q0 + 32768, q0 + 49152);
        }
        STEP_BODY(tb + 4, nA0, nA1);
        POLL_STEP(tb + 5); STEP_BODY(tb + 5, nB0, nB1);
        POLL_STEP(tb + 6); STEP_BODY(tb + 6, nC0, nC1);
        POLL_STEP(tb + 7); STEP_BODY(tb + 7, nD0, nD1);
    }

    // ---- tail: t = 2041..2044 use the final W window
    POLL_STEP(2041); STEP_BODY(2041, wA0, wA1);
    POLL_STEP(2042); STEP_BODY(2042, wB0, wB1);
    POLL_STEP(2043); STEP_BODY(2043, wC0, wC1);
    POLL_STEP(2044); STEP_BODY(2044, wD0, wD1);
    // ---- t = 2045..2047: per-step plain gx loads
    for (int t = 2045; t < Ss; ++t) {
        const uintx4* p = (const uintx4*)(gx + ((size_t)(t * 32 + wv) * 64 + lane) * 8);
        uintx4 ga = p[0], gb = p[1];
        POLL_STEP(t); STEP_BODY(t, ga, gb);
    }

    float* hfo = out + Bb * Ss * Hh;
    float* cfo = hfo + Bb * Hh;
#pragma unroll
    for (int r = 0; r < 4; ++r) {
        int b = 16 * mt + 4 * lg + r;
        hfo[b * Hh + j] = hl[r];
        cfo[b * Hh + j] = cst[r];
    }
}

extern "C" void kernel_launch(void* const* d_in, const int* in_sizes, int n_in,
                              void* d_out, int out_size, void* d_ws, size_t ws_size,
                              hipStream_t stream) {
    (void)in_sizes; (void)n_in; (void)out_size; (void)ws_size;
    const float* x  = (const float*)d_in[0];
    const float* h0 = (const float*)d_in[1];
    const float* c0 = (const float*)d_in[2];
    const float* Wf = (const float*)d_in[3]; const float* bf = (const float*)d_in[4];
    const float* Wi = (const float*)d_in[5]; const float* bi = (const float*)d_in[6];
    const float* Wc = (const float*)d_in[7]; const float* bc = (const float*)d_in[8];
    const float* Wo = (const float*)d_in[9]; const float* bo = (const float*)d_in[10];

    u32* data = (u32*)((char*)d_ws + DATA_OFF);
    u32* gx   = (u32*)((char*)d_ws + GX_OFF);

    // zero the exchange region: all-zero = "unwritten" under the bit14 validity code
    hipMemsetAsync(d_ws, 0, 65536, stream);

    hipLaunchKernelGGL(lstm_gx_kernel, dim3(2048), dim3(256), 0, stream,
                       x, Wf, bf, Wi, bi, Wc, bc, Wo, bo, gx);
    hipLaunchKernelGGL(lstm_rec10, dim3(8), dim3(256), 0, stream,
                       h0, c0, Wf, Wi, Wc, Wo, (float*)d_out, data, gx);
}